// Round 2
// baseline (150.902 us; speedup 1.0000x reference)
//
#include <hip/hip_runtime.h>

#define BROWS 524288
#define KBINS 64
#define GRID1 2048
// rows per block per outer iteration: 4 waves * 8 rows = 32 -> 8 iterations
#define ITERS (BROWS / (GRID1 * 32))

__global__ __launch_bounds__(256) void surv_fused(
    const float* __restrict__ inp, const float* __restrict__ yv,
    const int* __restrict__ ev, float* __restrict__ out,
    float* __restrict__ partials, unsigned* __restrict__ counter)
{
  const int tid  = threadIdx.x;
  const int lane = tid & 63;
  const int wave = tid >> 6;   // 0..3
  const int sub  = lane >> 4;  // row within 4-row group
  const int l16  = lane & 15;  // lane within row group

  const float A   = 2.8853900817779268f;   // 2*log2(e)  (logit scale in log2 domain)
  const float M2  = 0.28853900817779268f;  // 0.2*log2(e) (margin*scale in log2 domain)
  const float S0  = 0.018315638888734179f; // exp(-4)
  const float IS0 = 54.598150033144236f;   // exp(+4)
  const float LN2 = 0.6931471805599453f;

  float* cnt = out + 1;  // count[B,K] starts after the scalar loss
  float acc = 0.f;

  for (int it = 0; it < ITERS; ++it) {
    const int base = (it * GRID1 + blockIdx.x) * 32 + wave * 8;
    #pragma unroll
    for (int h = 0; h < 2; ++h) {
      const int rsub = base + h * 4;   // first row of this wave's 4-row group
      const int row  = rsub + sub;
      const float y = yv[row];
      const int   e = ev[row];
      const int   b = (int)y;
      const bool valid = (y >= 0.f) && (y < 64.f);
      const int b_eff = valid ? b : 127;              // sentinel: c==0 everywhere
      const int hi    = (e != 0) ? b_eff : 63;        // count = [b_eff, hi]
      const bool all1 = (e == 0) && (b_eff == 0);     // count all-ones -> min==1

      const float4 x = *reinterpret_cast<const float4*>(
          inp + (size_t)row * KBINS + l16 * 4);
      const float xa[4] = {x.x, x.y, x.z, x.w};

      float correct = 0.f, fev = 0.f, fcs = 0.f;
      #pragma unroll
      for (int j = 0; j < 4; ++j) {
        const int bin = l16 * 4 + j;
        const bool c = (bin >= b_eff) && (bin <= hi);
        const float mm = (c && !all1) ? 0.f : M2;      // margin where count==min
        const float t  = fmaf(xa[j], A, mm);           // log2-domain logit
        const float pen = __builtin_amdgcn_exp2f(t);   // exp(+logit)
        const float pe  = __builtin_amdgcn_exp2f(-t);  // exp(-logit)
        correct += c ? pe  : 0.f;
        fcs     += c ? 0.f : pe;
        fev     += c ? 0.f : pen;
      }

      #pragma unroll
      for (int m = 1; m < 16; m <<= 1) {
        correct += __shfl_xor(correct, m, 64);
        fev     += __shfl_xor(fev, m, 64);
        fcs     += __shfl_xor(fcs, m, 64);
      }

      // sum(count)==1  <=>  valid && (event || b==K-1)
      const bool is_event = valid && (e != 0 || b == KBINS - 1);
      const float lev = (__builtin_amdgcn_logf(correct + S0) +
                         __builtin_amdgcn_logf(fev + S0)) * LN2;
      const float lcs = __builtin_amdgcn_logf(
                            fmaf(fcs, IS0, fmaf(correct, fcs, 1.f))) * LN2;
      if (l16 == 0) acc += is_event ? lev : lcs;

      // count stores: broadcast row params, all 64 lanes write ONE row
      // -> each store instruction = 256B fully contiguous -> nt-safe
      const int pack = b_eff | (hi << 8);
      float* crow = cnt + (size_t)rsub * KBINS + lane;
      #pragma unroll
      for (int j = 0; j < 4; ++j) {
        const int pj = __shfl(pack, j * 16, 64);
        const int bj = pj & 0xff;
        const int hj = pj >> 8;
        const float c = (lane >= bj && lane <= hj) ? 1.f : 0.f;
        __builtin_nontemporal_store(c, crow + (size_t)j * KBINS);
      }
    }
  }

  // block reduction: acc nonzero at lanes {0,16,32,48}
  acc += __shfl_xor(acc, 16, 64);
  acc += __shfl_xor(acc, 32, 64);
  __shared__ float sm[4];
  __shared__ int amLast;
  if (lane == 0) sm[wave] = acc;
  __syncthreads();
  if (tid == 0) {
    partials[blockIdx.x] = (sm[0] + sm[1]) + (sm[2] + sm[3]);
    __threadfence();                       // release: partial visible device-wide
    unsigned old = atomicAdd(counter, 1u);
    amLast = (old == GRID1 - 1);
  }
  __syncthreads();
  if (amLast) {
    __threadfence();                       // acquire
    float s = 0.f;
    for (int i = tid; i < GRID1; i += 256)
      s += __hip_atomic_load(&partials[i], __ATOMIC_RELAXED,
                             __HIP_MEMORY_SCOPE_AGENT);
    #pragma unroll
    for (int m = 1; m < 64; m <<= 1) s += __shfl_xor(s, m, 64);
    __shared__ float sm2[4];
    if (lane == 0) sm2[wave] = s;
    __syncthreads();
    if (tid == 0) out[0] = ((sm2[0] + sm2[1]) + (sm2[2] + sm2[3])) *
                           (1.0f / (float)BROWS);
  }
}

extern "C" void kernel_launch(void* const* d_in, const int* in_sizes, int n_in,
                              void* d_out, int out_size, void* d_ws, size_t ws_size,
                              hipStream_t stream) {
  const float* inp = (const float*)d_in[0];
  const float* y   = (const float*)d_in[1];
  const int*   e   = (const int*)d_in[2];
  float* out      = (float*)d_out;
  float* partials = (float*)d_ws;                          // GRID1 floats
  unsigned* counter = (unsigned*)((char*)d_ws + 8192);     // after partials

  hipMemsetAsync(counter, 0, sizeof(unsigned), stream);
  surv_fused<<<GRID1, 256, 0, stream>>>(inp, y, e, out, partials, counter);
}